// Round 12
// baseline (4629.063 us; speedup 1.0000x reference)
//
#include <hip/hip_runtime.h>

// ---------- types / helpers ----------
typedef short short8 __attribute__((ext_vector_type(8)));
typedef __bf16 bf16x8 __attribute__((ext_vector_type(8)));
typedef float f32x4 __attribute__((ext_vector_type(4)));
typedef float f32x4v __attribute__((ext_vector_type(4)));
typedef unsigned short u16x4 __attribute__((ext_vector_type(4)));
typedef unsigned int uint2v __attribute__((ext_vector_type(2)));
typedef unsigned long long u64;

__device__ __forceinline__ unsigned short f2b(float f) {
  unsigned x = __builtin_bit_cast(unsigned, f);
  x = x + 0x7fffu + ((x >> 16) & 1u);   // RNE (finite inputs)
  return (unsigned short)(x >> 16);
}
__device__ __forceinline__ float b2f(unsigned short u) {
  unsigned x = ((unsigned)u) << 16;
  return __builtin_bit_cast(float, x);
}
__device__ __forceinline__ f32x4 mfma16(short8 a, short8 b, f32x4 c) {
  return __builtin_amdgcn_mfma_f32_16x16x32_bf16(
      __builtin_bit_cast(bf16x8, a), __builtin_bit_cast(bf16x8, b), c, 0, 0, 0);
}
typedef const __attribute__((address_space(1))) void* gas_p;
typedef __attribute__((address_space(3))) void* las_p;
__device__ __forceinline__ void gload_lds16(const void* g, void* l) {
  __builtin_amdgcn_global_load_lds((gas_p)g, (las_p)l, 16, 0, 0);
}

// sc0 ops: L1-bypassed, served by the CU's L2 (shared within an XCD).
__device__ __forceinline__ void load2_sc0(const u64* p0, const u64* p1,
                                          u64& v0, u64& v1) {
  asm volatile("global_load_dwordx2 %0, %2, off sc0\n\t"
               "global_load_dwordx2 %1, %3, off sc0\n\t"
               "s_waitcnt vmcnt(0)"
               : "=v"(v0), "=v"(v1) : "v"(p0), "v"(p1) : "memory");
}
__device__ __forceinline__ void store_sc0(unsigned* p, unsigned v) {
  asm volatile("global_store_dword %0, %1, off sc0" :: "v"(p), "v"(v) : "memory");
}

// ---------- conversion kernels ----------
__global__ __launch_bounds__(256) void k_cvt_bf16(const float* __restrict__ in,
                                                  unsigned short* __restrict__ out,
                                                  int n4) {
  int i = blockIdx.x * 256 + threadIdx.x;
  if (i >= n4) return;
  f32x4v v = *(const f32x4v*)(in + (size_t)i * 4);
  u16x4 o;
  o[0] = f2b(v[0]); o[1] = f2b(v[1]); o[2] = f2b(v[2]); o[3] = f2b(v[3]);
  *(u16x4*)(out + (size_t)i * 4) = o;
}

// hq/fq [b][0][i] = tag0 | bf16(h0[b][i]); [b][1][i] = 0  (dispatch-end flush
// makes these visible to every later scope - proven by R4-R10)
__global__ __launch_bounds__(256) void k_init_hq(const float* __restrict__ h0,
                                                 unsigned int* __restrict__ hq,
                                                 unsigned int* __restrict__ fq) {
  int idx = blockIdx.x * 256 + threadIdx.x;
  if (idx >= 8192) return;
  int b = idx >> 10, i = idx & 1023;
  unsigned v = (unsigned)f2b(h0[idx]);
  hq[(size_t)b * 2048 + i] = v;       hq[(size_t)b * 2048 + 1024 + i] = 0u;
  fq[(size_t)b * 2048 + i] = v;       fq[(size_t)b * 2048 + 1024 + i] = 0u;
}

__global__ void k_zero16(unsigned int* __restrict__ p) {
  if (threadIdx.x < 16) p[threadIdx.x] = 0u;
}

// out[c][r] = bf16(in[r][c]);  R,C multiples of 32
__global__ __launch_bounds__(256) void k_transpose_bf16(const float* __restrict__ in,
                                                        unsigned short* __restrict__ out,
                                                        int R, int C) {
  __shared__ unsigned short tile[32][33];
  int c0 = blockIdx.x * 32, r0 = blockIdx.y * 32;
  int tx = threadIdx.x & 31, ty = threadIdx.x >> 5;
#pragma unroll
  for (int i = 0; i < 4; i++) {
    int r = ty + i * 8;
    tile[r][tx] = f2b(in[(size_t)(r0 + r) * C + c0 + tx]);
  }
  __syncthreads();
#pragma unroll
  for (int i = 0; i < 4; i++) {
    int rr = ty + i * 8;
    out[(size_t)(c0 + rr) * R + r0 + tx] = tile[tx][rr];
  }
}

// ---------- GEMM1: drive = silu(u)*silu(v)+w ----------
__global__ __launch_bounds__(256) void k_gemm_drive(const unsigned short* __restrict__ xb,
                                                    const unsigned short* __restrict__ WinT,
                                                    const float* __restrict__ b_in,
                                                    unsigned short* __restrict__ drive) {
  __shared__ unsigned short At[128 * 32];
  __shared__ unsigned short Bt[3][64 * 32];
  const int tid = threadIdx.x;
  const int w = tid >> 6, l = tid & 63;
  const int wm = w >> 1, wn = w & 1;
  const int lr = l & 15, lk = (l >> 4) * 8;
  const int m0 = blockIdx.x * 128;
  const int j0 = blockIdx.y * 64;
  f32x4 acc[3][4][2];
#pragma unroll
  for (int s = 0; s < 3; s++)
#pragma unroll
    for (int mi = 0; mi < 4; mi++)
#pragma unroll
      for (int ni = 0; ni < 2; ni++)
#pragma unroll
        for (int e = 0; e < 4; e++) acc[s][mi][ni][e] = 0.f;

  const int sr = tid >> 2;
  const int skb = (tid & 3) * 8;
  for (int kt = 0; kt < 32; kt++) {
    const int k0 = kt * 32;
    gload_lds16(xb + (size_t)(m0 + sr) * 1024 + k0 + skb, &At[w * 512]);
    gload_lds16(xb + (size_t)(m0 + 64 + sr) * 1024 + k0 + skb, &At[2048 + w * 512]);
#pragma unroll
    for (int s = 0; s < 3; s++)
      gload_lds16(WinT + (size_t)(s * 1024 + j0 + sr) * 1024 + k0 + skb, &Bt[s][w * 512]);
    __syncthreads();
    short8 Af[4], Bf[3][2];
#pragma unroll
    for (int mi = 0; mi < 4; mi++)
      Af[mi] = *(const short8*)&At[(wm * 64 + mi * 16 + lr) * 32 + lk];
#pragma unroll
    for (int s = 0; s < 3; s++)
#pragma unroll
      for (int ni = 0; ni < 2; ni++)
        Bf[s][ni] = *(const short8*)&Bt[s][(wn * 32 + ni * 16 + lr) * 32 + lk];
#pragma unroll
    for (int s = 0; s < 3; s++)
#pragma unroll
      for (int mi = 0; mi < 4; mi++)
#pragma unroll
        for (int ni = 0; ni < 2; ni++)
          acc[s][mi][ni] = mfma16(Af[mi], Bf[s][ni], acc[s][mi][ni]);
    __syncthreads();
  }
#pragma unroll
  for (int ni = 0; ni < 2; ni++) {
    const int c = j0 + wn * 32 + ni * 16 + lr;
    const float bu = b_in[c], bv = b_in[1024 + c], bw = b_in[2048 + c];
#pragma unroll
    for (int mi = 0; mi < 4; mi++) {
      const int r0 = m0 + wm * 64 + mi * 16 + (l >> 4) * 4;
#pragma unroll
      for (int e = 0; e < 4; e++) {
        float u = acc[0][mi][ni][e] + bu;
        float v = acc[1][mi][ni][e] + bv;
        float wv = acc[2][mi][ni][e] + bw;
        float su = u / (1.f + __expf(-u));
        float sv = v / (1.f + __expf(-v));
        drive[(size_t)(r0 + e) * 1024 + c] = f2b(su * sv + wv);
      }
    }
  }
}

// ---------- persistent scan v12: verified XCD rings + latched fallback ----------
// 256 WGs x 1024 thr (1/CU - co-residency PROVEN by R10). Ring=batch, 32 WGs.
// Claims: XCC_ID preferred, round-robin overflow via global counters ->
//   all 8x32 slots filled for ANY XCC_ID behavior (pigeonhole).
// Coherence test: 6 deadlined rounds on scratch tst[] with increasing tags and
//   alternating phases (forces stale-L2-line reuse; cross-L2 ring must fail).
//   Votes: one packed atomic word per ring (hi=votes, lo=oks).
// Steady state: producers ALWAYS sc1-publish to mirror hq (R10-proven path);
//   if ring verified, also sc0-publish to fq. Consumers poll fq (sc0, fast,
//   500us deadline -> permanent latch to mirror). No unbounded unproven spin.
__global__ __launch_bounds__(1024, 4) void k_scan(const unsigned short* __restrict__ WgT,
                                                  const unsigned short* __restrict__ WrT,
                                                  const float* __restrict__ b_gate,
                                                  const float* __restrict__ b_rec,
                                                  const unsigned short* __restrict__ drive,
                                                  unsigned int* __restrict__ hq,
                                                  unsigned int* __restrict__ fq,
                                                  unsigned int* __restrict__ tst,
                                                  unsigned int* __restrict__ cnt,
                                                  unsigned int* __restrict__ vote,
                                                  unsigned short* __restrict__ hs,
                                                  float* __restrict__ final_h) {
  const int tid = threadIdx.x;        // 0..1023
  const int w = tid >> 6, l = tid & 63;

  __shared__ unsigned int claim_sh;
  __shared__ int lds_ok;
  __shared__ unsigned int tileh[512];   // h_t of batch b: bf16x2 pairs (2KB)
  __shared__ float buf[4][3][32];       // [kq][mat][col] row-0 partials

  // ---- claim (ring, slot): XCD-preferred, overflow-safe ----
  if (tid == 0) {
    unsigned xcd;
    asm volatile("s_getreg_b32 %0, hwreg(HW_REG_XCC_ID)" : "=s"(xcd));
    xcd &= 7u;
    unsigned ring = 0, slot = 0;
    for (int k = 0; k < 8; ++k) {       // bounded; pigeonhole guarantees slot<32
      ring = (xcd + (unsigned)k) & 7u;
      slot = atomicAdd(&cnt[ring], 1u);
      if (slot < 32u) break;
    }
    claim_sh = (ring << 16) | slot;
    lds_ok = 1;
  }
  __syncthreads();
  const int b = (int)(claim_sh >> 16);
  const int s = (int)(claim_sh & 0xffffu);

  // ---- MFMA-wave setup (w<12): B-frags -> registers ----
  const int mat = w >> 2, kq = w & 3;
  const int lr = l & 15, ko = l >> 4;
  const bool av = (lr == 0);
  short8 Breg[2][8];
  if (w < 12) {
    const unsigned short* WT = (mat == 2) ? WrT : WgT;
    const int rowbase = ((mat == 1) ? 1024 : 0) + s * 32;
#pragma unroll
    for (int tile = 0; tile < 2; ++tile)
#pragma unroll
      for (int ks = 0; ks < 8; ++ks)
        Breg[tile][ks] = *(const short8*)&WT[(size_t)(rowbase + tile * 16 + lr) * 1024 +
                                             kq * 256 + ks * 32 + ko * 8];
  }

  const bool isld = tid >= 768;
  const int q = tid - 768;              // 0..255
  const bool isfin = tid < 32;
  const int fcol = s * 32 + tid;        // valid when isfin
  float bgv = 0.f, bgt = 0.f, brc = 0.f;
  if (isfin) { bgv = b_gate[fcol]; bgt = b_gate[1024 + fcol]; brc = b_rec[fcol]; }

  // ---- 6-round deadlined coherence test on tst[b] ----
  {
    bool tok = true;
    for (int r = 1; r <= 6; ++r) {
      const int tp = r & 1;
      const unsigned rtag = 0xE000u + (unsigned)r;
      if (isfin)
        store_sc0(tst + ((size_t)(b * 2 + tp) << 10) + fcol, (rtag << 16) | 1u);
      if (isld && tok) {
        const u64* w0 = (const u64*)(tst + ((size_t)(b * 2 + tp) << 10)) + 2 * q;
        const u64 t0r = __builtin_amdgcn_s_memrealtime();
        for (;;) {
          u64 v0, v1;
          load2_sc0(w0, w0 + 1, v0, v1);
          const bool ok = (((unsigned)v0 >> 16) == rtag) &
                          (((unsigned)(v0 >> 32) >> 16) == rtag) &
                          (((unsigned)v1 >> 16) == rtag) &
                          (((unsigned)(v1 >> 32) >> 16) == rtag);
          if (ok) break;
          if (__builtin_amdgcn_s_memrealtime() - t0r > 20000) { tok = false; break; }
        }
      }
      __syncthreads();
    }
    if (isld && !tok) lds_ok = 0;       // racing 0-stores are benign
    __syncthreads();
    if (tid == 0) {
      const unsigned my = 0x10000u | (unsigned)lds_ok;
      (void)__hip_atomic_fetch_add(&vote[b], my, __ATOMIC_RELAXED,
                                   __HIP_MEMORY_SCOPE_AGENT);
      unsigned vv;
      do {
        vv = __hip_atomic_load(&vote[b], __ATOMIC_RELAXED, __HIP_MEMORY_SCOPE_AGENT);
      } while ((vv >> 16) < 32u);       // bounded: all 32 members vote
      claim_sh = ((vv & 0xffffu) == 32u) ? 1u : 0u;
    }
    __syncthreads();
  }
  const bool rok = (claim_sh != 0u);
  bool mir = !rok;                      // per-lane latched fallback

  // ---- main recurrence loop ----
  for (int t = 0; t < 2048; ++t) {
    const int p = t & 1;
    unsigned short dpf = 0;
    if (isfin) dpf = drive[(size_t)(b * 2048 + t) * 1024 + fcol];

    if (isld) {
      const unsigned tg = (unsigned)t;
      u64 v0 = 0, v1 = 0;
      if (!mir) {   // fast path: sc0 over (presumed) shared L2, deadlined
        const u64* f0 = (const u64*)(fq + (size_t)(b * 2 + p) * 1024) + 2 * q;
        const u64 t0r = __builtin_amdgcn_s_memrealtime();
        for (;;) {
          load2_sc0(f0, f0 + 1, v0, v1);
          const bool ok = (((unsigned)v0 >> 16) == tg) &
                          (((unsigned)(v0 >> 32) >> 16) == tg) &
                          (((unsigned)v1 >> 16) == tg) &
                          (((unsigned)(v1 >> 32) >> 16) == tg);
          if (ok) break;
          if (__builtin_amdgcn_s_memrealtime() - t0r > 50000) { mir = true; break; }
        }
      }
      if (mir) {    // mirror path: R10-proven sc1 protocol (unbounded OK)
        const u64* hb = (const u64*)(hq + (size_t)(b * 2 + p) * 1024) + 2 * q;
        unsigned pend = 3u;
        do {
          if (pend & 1u)
            v0 = __hip_atomic_load(hb, __ATOMIC_RELAXED, __HIP_MEMORY_SCOPE_AGENT);
          if (pend & 2u)
            v1 = __hip_atomic_load(hb + 1, __ATOMIC_RELAXED, __HIP_MEMORY_SCOPE_AGENT);
          unsigned np = 0;
          if ((((unsigned)v0 >> 16) != tg) | (((unsigned)(v0 >> 32) >> 16) != tg))
            np |= 1u;
          if ((((unsigned)v1 >> 16) != tg) | (((unsigned)(v1 >> 32) >> 16) != tg))
            np |= 2u;
          pend = np;
        } while (pend);
      }
      uint2v pk;
      pk[0] = __builtin_amdgcn_perm((unsigned)(v0 >> 32), (unsigned)v0, 0x05040100u);
      pk[1] = __builtin_amdgcn_perm((unsigned)(v1 >> 32), (unsigned)v1, 0x05040100u);
      *(uint2v*)&tileh[2 * q] = pk;
    }
    __syncthreads();   // tileh(t) complete

    if (w < 12) {
      f32x4 a0, a1;
#pragma unroll
      for (int e = 0; e < 4; ++e) { a0[e] = 0.f; a1[e] = 0.f; }
      const char* base = (const char*)tileh + kq * 512 + ko * 16;
#pragma unroll
      for (int ks = 0; ks < 8; ++ks) {
        short8 Af;
#pragma unroll
        for (int e = 0; e < 8; ++e) Af[e] = 0;
        if (av) Af = *(const short8*)(base + ks * 64);
        a0 = mfma16(Af, Breg[0][ks], a0);
        a1 = mfma16(Af, Breg[1][ks], a1);
      }
      if (l < 16) {
        buf[kq][mat][l] = a0[0];
        buf[kq][mat][16 + l] = a1[0];
      }
    }
    __syncthreads();   // buf complete; tileh free for t+1

    if (isfin) {
      const float gv = ((buf[0][0][tid] + buf[1][0][tid]) +
                        (buf[2][0][tid] + buf[3][0][tid])) + bgv;
      const float gt = ((buf[0][1][tid] + buf[1][1][tid]) +
                        (buf[2][1][tid] + buf[3][1][tid])) + bgt;
      const float rc = ((buf[0][2][tid] + buf[1][2][tid]) +
                        (buf[2][2][tid] + buf[3][2][tid])) + brc;
      const float sgv = 1.f / (1.f + __expf(-gv));
      const float sgt = 1.f / (1.f + __expf(-gt));
      const float gate = sgv * gt * sgt;  // sigmoid(gv) * silu(gt)
      const float nh = gate * rc + (1.f - gate) * b2f(dpf);
      const unsigned short nhb = f2b(nh);
      const unsigned pkv = (((unsigned)(t + 1)) << 16) | (unsigned)nhb;
      const size_t poff = (size_t)(b * 2 + (p ^ 1)) * 1024 + fcol;
      if (rok) store_sc0(fq + poff, pkv);            // fast local copy
      __hip_atomic_store(hq + poff, pkv,             // mirror: ALWAYS (liveness)
                         __ATOMIC_RELAXED, __HIP_MEMORY_SCOPE_AGENT);
      hs[(size_t)(b * 2048 + t) * 1024 + fcol] = nhb;
      if (t == 2047) final_h[b * 1024 + fcol] = nh;
    }
  }
}

// ---------- GEMM3: out = hs @ W_out + b_out ----------
__global__ __launch_bounds__(256) void k_gemm_out(const unsigned short* __restrict__ hs,
                                                  const unsigned short* __restrict__ WoT,
                                                  const float* __restrict__ b_out,
                                                  float* __restrict__ out) {
  __shared__ unsigned short At[128 * 32];
  __shared__ unsigned short Bt[128 * 32];
  const int tid = threadIdx.x;
  const int w = tid >> 6, l = tid & 63;
  const int wm = w >> 1, wn = w & 1;
  const int lr = l & 15, lk = (l >> 4) * 8;
  const int m0 = blockIdx.x * 128;
  const int n0 = blockIdx.y * 128;
  f32x4 acc[4][4];
#pragma unroll
  for (int mi = 0; mi < 4; mi++)
#pragma unroll
    for (int ni = 0; ni < 4; ni++)
#pragma unroll
      for (int e = 0; e < 4; e++) acc[mi][ni][e] = 0.f;

  const int sr = tid >> 2;
  const int skb = (tid & 3) * 8;
  for (int kt = 0; kt < 32; kt++) {
    const int k0 = kt * 32;
    gload_lds16(hs + (size_t)(m0 + sr) * 1024 + k0 + skb, &At[w * 512]);
    gload_lds16(hs + (size_t)(m0 + 64 + sr) * 1024 + k0 + skb, &At[2048 + w * 512]);
    gload_lds16(WoT + (size_t)(n0 + sr) * 1024 + k0 + skb, &Bt[w * 512]);
    gload_lds16(WoT + (size_t)(n0 + 64 + sr) * 1024 + k0 + skb, &Bt[2048 + w * 512]);
    __syncthreads();
    short8 Af[4], Bf[4];
#pragma unroll
    for (int mi = 0; mi < 4; mi++)
      Af[mi] = *(const short8*)&At[(wm * 64 + mi * 16 + lr) * 32 + lk];
#pragma unroll
    for (int ni = 0; ni < 4; ni++)
      Bf[ni] = *(const short8*)&Bt[(wn * 64 + ni * 16 + lr) * 32 + lk];
#pragma unroll
    for (int mi = 0; mi < 4; mi++)
#pragma unroll
      for (int ni = 0; ni < 4; ni++)
        acc[mi][ni] = mfma16(Af[mi], Bf[ni], acc[mi][ni]);
    __syncthreads();
  }
#pragma unroll
  for (int ni = 0; ni < 4; ni++) {
    const int c = n0 + wn * 64 + ni * 16 + lr;
    const float bo = b_out[c];
#pragma unroll
    for (int mi = 0; mi < 4; mi++) {
      const int r0 = m0 + wm * 64 + mi * 16 + (l >> 4) * 4;
#pragma unroll
      for (int e = 0; e < 4; e++)
        out[(size_t)(r0 + e) * 1024 + c] = acc[mi][ni][e] + bo;
    }
  }
}

// ---------- launch ----------
extern "C" void kernel_launch(void* const* d_in, const int* in_sizes, int n_in,
                              void* d_out, int out_size, void* d_ws, size_t ws_size,
                              hipStream_t stream) {
  const float* x      = (const float*)d_in[0];
  const float* h0     = (const float*)d_in[1];
  const float* W_in   = (const float*)d_in[2];
  const float* b_in   = (const float*)d_in[3];
  const float* W_gate = (const float*)d_in[4];
  const float* b_gate = (const float*)d_in[5];
  const float* W_rec  = (const float*)d_in[6];
  const float* b_rec  = (const float*)d_in[7];
  const float* W_out  = (const float*)d_in[8];
  const float* b_out  = (const float*)d_in[9];
  float* outp = (float*)d_out;

  size_t off = 0;
  auto alloc = [&](size_t bytes) {
    void* p = (char*)d_ws + off;
    off += (bytes + 255) & ~(size_t)255;
    return p;
  };
  unsigned short* xb    = (unsigned short*)alloc((size_t)16777216 * 2);
  unsigned short* WinT  = (unsigned short*)alloc((size_t)3072 * 1024 * 2);
  unsigned short* WgT   = (unsigned short*)alloc((size_t)2048 * 1024 * 2);
  unsigned short* WrT   = (unsigned short*)alloc((size_t)1024 * 1024 * 2);
  unsigned short* WoT   = (unsigned short*)alloc((size_t)1024 * 1024 * 2);
  unsigned short* drive = (unsigned short*)alloc((size_t)16777216 * 2);
  unsigned short* hs    = (unsigned short*)alloc((size_t)16777216 * 2);
  unsigned int*   hq    = (unsigned int*)alloc((size_t)8 * 2 * 1024 * 4);  // mirror
  unsigned int*   fq    = (unsigned int*)alloc((size_t)8 * 2 * 1024 * 4);  // fast
  unsigned int*   tst   = (unsigned int*)alloc((size_t)8 * 2 * 1024 * 4);  // test
  unsigned int*   cnt   = (unsigned int*)alloc((size_t)16 * 4);            // cnt[8]
  unsigned int*   vote  = cnt + 8;                                         // vote[8]

  // conversions / init
  k_cvt_bf16<<<16384, 256, 0, stream>>>(x, xb, 4194304);
  k_transpose_bf16<<<dim3(96, 32), 256, 0, stream>>>(W_in, WinT, 1024, 3072);
  k_transpose_bf16<<<dim3(64, 32), 256, 0, stream>>>(W_gate, WgT, 1024, 2048);
  k_transpose_bf16<<<dim3(32, 32), 256, 0, stream>>>(W_rec, WrT, 1024, 1024);
  k_transpose_bf16<<<dim3(32, 32), 256, 0, stream>>>(W_out, WoT, 1024, 1024);
  k_init_hq<<<32, 256, 0, stream>>>(h0, hq, fq);
  k_zero16<<<1, 16, 0, stream>>>(cnt);

  // drive = silu(u)*silu(v)+w
  k_gemm_drive<<<dim3(128, 16), 256, 0, stream>>>(xb, WinT, b_in, drive);
  // sequential recurrence: verified XCD rings + latched sc1 fallback
  k_scan<<<256, 1024, 0, stream>>>(WgT, WrT, b_gate, b_rec, drive, hq, fq, tst,
                                   cnt, vote, hs, outp + 16777216);
  // out = hs @ W_out + b_out
  k_gemm_out<<<dim3(128, 8), 256, 0, stream>>>(hs, WoT, b_out, outp);
}

// Round 13
// 4357.671 us; speedup vs baseline: 1.0623x; 1.0623x over previous
//
#include <hip/hip_runtime.h>

// ---------- types / helpers ----------
typedef short short8 __attribute__((ext_vector_type(8)));
typedef __bf16 bf16x8 __attribute__((ext_vector_type(8)));
typedef float f32x4 __attribute__((ext_vector_type(4)));
typedef float f32x4v __attribute__((ext_vector_type(4)));
typedef unsigned short u16x4 __attribute__((ext_vector_type(4)));
typedef unsigned int uint2v __attribute__((ext_vector_type(2)));
typedef unsigned long long u64;

__device__ __forceinline__ unsigned short f2b(float f) {
  unsigned x = __builtin_bit_cast(unsigned, f);
  x = x + 0x7fffu + ((x >> 16) & 1u);   // RNE (finite inputs)
  return (unsigned short)(x >> 16);
}
__device__ __forceinline__ float b2f(unsigned short u) {
  unsigned x = ((unsigned)u) << 16;
  return __builtin_bit_cast(float, x);
}
__device__ __forceinline__ f32x4 mfma16(short8 a, short8 b, f32x4 c) {
  return __builtin_amdgcn_mfma_f32_16x16x32_bf16(
      __builtin_bit_cast(bf16x8, a), __builtin_bit_cast(bf16x8, b), c, 0, 0, 0);
}
typedef const __attribute__((address_space(1))) void* gas_p;
typedef __attribute__((address_space(3))) void* las_p;
__device__ __forceinline__ void gload_lds16(const void* g, void* l) {
  __builtin_amdgcn_global_load_lds((gas_p)g, (las_p)l, 16, 0, 0);
}

#define NPH 8   // exchange depth: skew up to 6 steps absorbed

// ---------- conversion kernels ----------
__global__ __launch_bounds__(256) void k_cvt_bf16(const float* __restrict__ in,
                                                  unsigned short* __restrict__ out,
                                                  int n4) {
  int i = blockIdx.x * 256 + threadIdx.x;
  if (i >= n4) return;
  f32x4v v = *(const f32x4v*)(in + (size_t)i * 4);
  u16x4 o;
  o[0] = f2b(v[0]); o[1] = f2b(v[1]); o[2] = f2b(v[2]); o[3] = f2b(v[3]);
  *(u16x4*)(out + (size_t)i * 4) = o;
}

// hq[b][0][i] = tag0 | bf16(h0[b][i]); slots 1..7 zeroed (tag 0 never matches
// the first expected tag at those slots)
__global__ __launch_bounds__(256) void k_init_hq8(const float* __restrict__ h0,
                                                  unsigned int* __restrict__ hq) {
  int idx = blockIdx.x * 256 + threadIdx.x;
  if (idx >= 8192) return;
  int b = idx >> 10, i = idx & 1023;
  size_t base = (size_t)b * (NPH * 1024);
  hq[base + i] = (unsigned int)f2b(h0[idx]);
#pragma unroll
  for (int s = 1; s < NPH; ++s) hq[base + s * 1024 + i] = 0u;
}

__global__ void k_zero_prog(unsigned int* __restrict__ p) {
  if (threadIdx.x < 256) p[threadIdx.x] = 0u;
}

// out[c][r] = bf16(in[r][c]);  R,C multiples of 32
__global__ __launch_bounds__(256) void k_transpose_bf16(const float* __restrict__ in,
                                                        unsigned short* __restrict__ out,
                                                        int R, int C) {
  __shared__ unsigned short tile[32][33];
  int c0 = blockIdx.x * 32, r0 = blockIdx.y * 32;
  int tx = threadIdx.x & 31, ty = threadIdx.x >> 5;
#pragma unroll
  for (int i = 0; i < 4; i++) {
    int r = ty + i * 8;
    tile[r][tx] = f2b(in[(size_t)(r0 + r) * C + c0 + tx]);
  }
  __syncthreads();
#pragma unroll
  for (int i = 0; i < 4; i++) {
    int rr = ty + i * 8;
    out[(size_t)(c0 + rr) * R + r0 + tx] = tile[tx][rr];
  }
}

// ---------- GEMM1: drive = silu(u)*silu(v)+w ----------
__global__ __launch_bounds__(256) void k_gemm_drive(const unsigned short* __restrict__ xb,
                                                    const unsigned short* __restrict__ WinT,
                                                    const float* __restrict__ b_in,
                                                    unsigned short* __restrict__ drive) {
  __shared__ unsigned short At[128 * 32];
  __shared__ unsigned short Bt[3][64 * 32];
  const int tid = threadIdx.x;
  const int w = tid >> 6, l = tid & 63;
  const int wm = w >> 1, wn = w & 1;
  const int lr = l & 15, lk = (l >> 4) * 8;
  const int m0 = blockIdx.x * 128;
  const int j0 = blockIdx.y * 64;
  f32x4 acc[3][4][2];
#pragma unroll
  for (int s = 0; s < 3; s++)
#pragma unroll
    for (int mi = 0; mi < 4; mi++)
#pragma unroll
      for (int ni = 0; ni < 2; ni++)
#pragma unroll
        for (int e = 0; e < 4; e++) acc[s][mi][ni][e] = 0.f;

  const int sr = tid >> 2;
  const int skb = (tid & 3) * 8;
  for (int kt = 0; kt < 32; kt++) {
    const int k0 = kt * 32;
    gload_lds16(xb + (size_t)(m0 + sr) * 1024 + k0 + skb, &At[w * 512]);
    gload_lds16(xb + (size_t)(m0 + 64 + sr) * 1024 + k0 + skb, &At[2048 + w * 512]);
#pragma unroll
    for (int s = 0; s < 3; s++)
      gload_lds16(WinT + (size_t)(s * 1024 + j0 + sr) * 1024 + k0 + skb, &Bt[s][w * 512]);
    __syncthreads();
    short8 Af[4], Bf[3][2];
#pragma unroll
    for (int mi = 0; mi < 4; mi++)
      Af[mi] = *(const short8*)&At[(wm * 64 + mi * 16 + lr) * 32 + lk];
#pragma unroll
    for (int s = 0; s < 3; s++)
#pragma unroll
      for (int ni = 0; ni < 2; ni++)
        Bf[s][ni] = *(const short8*)&Bt[s][(wn * 32 + ni * 16 + lr) * 32 + lk];
#pragma unroll
    for (int s = 0; s < 3; s++)
#pragma unroll
      for (int mi = 0; mi < 4; mi++)
#pragma unroll
        for (int ni = 0; ni < 2; ni++)
          acc[s][mi][ni] = mfma16(Af[mi], Bf[s][ni], acc[s][mi][ni]);
    __syncthreads();
  }
#pragma unroll
  for (int ni = 0; ni < 2; ni++) {
    const int c = j0 + wn * 32 + ni * 16 + lr;
    const float bu = b_in[c], bv = b_in[1024 + c], bw = b_in[2048 + c];
#pragma unroll
    for (int mi = 0; mi < 4; mi++) {
      const int r0 = m0 + wm * 64 + mi * 16 + (l >> 4) * 4;
#pragma unroll
      for (int e = 0; e < 4; e++) {
        float u = acc[0][mi][ni][e] + bu;
        float v = acc[1][mi][ni][e] + bv;
        float wv = acc[2][mi][ni][e] + bw;
        float su = u / (1.f + __expf(-u));
        float sv = v / (1.f + __expf(-v));
        drive[(size_t)(r0 + e) * 1024 + c] = f2b(su * sv + wv);
      }
    }
  }
}

// ---------- persistent scan v13: R10 + 8-phase skewed exchange ----------
// 256 WGs x 1024 thr (1/CU). Ring=batch b=g>>5, slot s=g&31, 32 feats/WG.
// Exchange: hq[b][t&7][1024] tagged words ((t<<16)|bf16), sc1 agent-scope
// (R10-proven). NEW: 8 slots allow WGs to DRIFT up to 6 steps -> per-step
// jitter averages instead of max-of-32 amplifying (the R10 residual).
// Back-pressure: publishing h_{t+1} overwrites h_{t-7}; legal iff all mates
// published h_{t-6} (=> consumed h_{t-7}): check min(prog[b][*]) >= t-6.
// prog[b][s] stored by tid0 AFTER the wave's publish instr (program order) and
// after bar-ordered consumption of h_t -> inference sound under relaxed mem.
// Wave 0 lanes 32-63 prefetch prog during the poll phase (off critical path);
// wave-wide __all gates publish; rare-fail path re-loads (bounded by mates'
// liveness -> no deadlock: h_t cannot be overwritten before its consumers
// publish t+1, so every poll target eventually arrives).
__global__ __launch_bounds__(1024, 4) void k_scan(const unsigned short* __restrict__ WgT,
                                                  const unsigned short* __restrict__ WrT,
                                                  const float* __restrict__ b_gate,
                                                  const float* __restrict__ b_rec,
                                                  const unsigned short* __restrict__ drive,
                                                  unsigned int* __restrict__ hq,
                                                  unsigned int* __restrict__ prog,
                                                  unsigned short* __restrict__ hs,
                                                  float* __restrict__ final_h) {
  const int g = blockIdx.x;           // 0..255
  const int b = g >> 5;               // batch / ring id
  const int s = g & 31;               // slot in ring
  const int tid = threadIdx.x;        // 0..1023
  const int w = tid >> 6, l = tid & 63;

  __shared__ unsigned int tileh[512];   // h_t of batch b: packed bf16x2 (2KB)
  __shared__ float buf[4][3][32];       // [kq][mat][col] row-0 partials

  // ---- MFMA-wave setup (w<12): B-frags -> registers (2 tiles x 8 = 64 VGPR) ----
  const int mat = w >> 2, kq = w & 3;
  const int lr = l & 15, ko = l >> 4;
  const bool av = (lr == 0);            // A row-0 carrier lanes
  short8 Breg[2][8];
  if (w < 12) {
    const unsigned short* WT = (mat == 2) ? WrT : WgT;
    const int rowbase = ((mat == 1) ? 1024 : 0) + s * 32;
#pragma unroll
    for (int tile = 0; tile < 2; ++tile)
#pragma unroll
      for (int ks = 0; ks < 8; ++ks)
        Breg[tile][ks] = *(const short8*)&WT[(size_t)(rowbase + tile * 16 + lr) * 1024 +
                                             kq * 256 + ks * 32 + ko * 8];
  }

  // ---- poller setup (waves 12-15): lane q owns u64 words 2q, 2q+1 ----
  const bool isld = tid >= 768;
  const int q = tid - 768;              // 0..255

  // ---- finisher setup (tid<32): feature f = tid ----
  const bool isfin = tid < 32;
  const int fcol = s * 32 + tid;        // feature within batch (tid<32)
  float bgv = 0.f, bgt = 0.f, brc = 0.f;
  if (isfin) { bgv = b_gate[fcol]; bgt = b_gate[1024 + fcol]; brc = b_rec[fcol]; }

  for (int t = 0; t < 2048; ++t) {
    unsigned short dpf = 0;
    if (isfin) dpf = drive[(size_t)(b * 2048 + t) * 1024 + fcol];  // cached

    // ---- wave 0 lanes 32-63: prefetch ring progress (off critical path) ----
    unsigned ppv = 0u;
    if (w == 0 && l >= 32)
      ppv = __hip_atomic_load(prog + b * 32 + (l - 32), __ATOMIC_RELAXED,
                              __HIP_MEMORY_SCOPE_AGENT);

    if (isld) {  // ---- poll slot t&7 (tags == t), pack to LDS ----
      const unsigned tg = (unsigned)t;
      const u64* hb = (const u64*)(hq + ((size_t)(b * NPH + (t & 7)) << 10));
      u64 v0 = 0, v1 = 0;
      unsigned pend = 3u;
      do {
        if (pend & 1u)
          v0 = __hip_atomic_load(hb + 2 * q, __ATOMIC_RELAXED,
                                 __HIP_MEMORY_SCOPE_AGENT);
        if (pend & 2u)
          v1 = __hip_atomic_load(hb + 2 * q + 1, __ATOMIC_RELAXED,
                                 __HIP_MEMORY_SCOPE_AGENT);
        unsigned np = 0;
        if ((((unsigned)v0 >> 16) != tg) | (((unsigned)(v0 >> 32) >> 16) != tg))
          np |= 1u;
        if ((((unsigned)v1 >> 16) != tg) | (((unsigned)(v1 >> 32) >> 16) != tg))
          np |= 2u;
        pend = np;
      } while (pend);
      uint2v pk;
      pk[0] = __builtin_amdgcn_perm((unsigned)(v0 >> 32), (unsigned)v0, 0x05040100u);
      pk[1] = __builtin_amdgcn_perm((unsigned)(v1 >> 32), (unsigned)v1, 0x05040100u);
      *(uint2v*)&tileh[2 * q] = pk;
    }
    __syncthreads();   // tileh(t) complete

    // ---- MFMA: 16 per wave (2 col-tiles x 8 k-slices), row 0 = batch ----
    if (w < 12) {
      f32x4 a0, a1;
#pragma unroll
      for (int e = 0; e < 4; ++e) { a0[e] = 0.f; a1[e] = 0.f; }
      const char* base = (const char*)tileh + kq * 512 + ko * 16;
#pragma unroll
      for (int ks = 0; ks < 8; ++ks) {
        short8 Af;
#pragma unroll
        for (int e = 0; e < 8; ++e) Af[e] = 0;
        if (av) Af = *(const short8*)(base + ks * 64);
        a0 = mfma16(Af, Breg[0][ks], a0);
        a1 = mfma16(Af, Breg[1][ks], a1);
      }
      if (l < 16) {   // D row 0 lives in lanes 0-15, reg 0
        buf[kq][mat][l] = a0[0];
        buf[kq][mat][16 + l] = a1[0];
      }
    }
    __syncthreads();   // buf complete; tileh free for t+1

    // ---- back-pressure gate (wave 0, wave-wide): min(prog) >= t-6 ----
    if (w == 0) {
      bool pok = (l < 32) || ((int)ppv >= t - 6);
      while (!__all(pok)) {
        __builtin_amdgcn_s_sleep(1);
        if (l >= 32)
          ppv = __hip_atomic_load(prog + b * 32 + (l - 32), __ATOMIC_RELAXED,
                                  __HIP_MEMORY_SCOPE_AGENT);
        pok = (l < 32) || ((int)ppv >= t - 6);
      }
    }

    // ---- finisher: K-quarter reduce + gate math + tagged publish ----
    if (isfin) {
      const float gv = ((buf[0][0][tid] + buf[1][0][tid]) +
                        (buf[2][0][tid] + buf[3][0][tid])) + bgv;
      const float gt = ((buf[0][1][tid] + buf[1][1][tid]) +
                        (buf[2][1][tid] + buf[3][1][tid])) + bgt;
      const float rc = ((buf[0][2][tid] + buf[1][2][tid]) +
                        (buf[2][2][tid] + buf[3][2][tid])) + brc;
      const float sgv = 1.f / (1.f + __expf(-gv));
      const float sgt = 1.f / (1.f + __expf(-gt));
      const float gate = sgv * gt * sgt;  // sigmoid(gv) * silu(gt)
      const float nh = gate * rc + (1.f - gate) * b2f(dpf);
      const unsigned short nhb = f2b(nh);
      __hip_atomic_store(hq + ((size_t)(b * NPH + ((t + 1) & 7)) << 10) + fcol,
                         (((unsigned)(t + 1)) << 16) | (unsigned)nhb,
                         __ATOMIC_RELAXED, __HIP_MEMORY_SCOPE_AGENT);
      hs[(size_t)(b * 2048 + t) * 1024 + fcol] = nhb;
      if (t == 2047) final_h[b * 1024 + fcol] = nh;
      if (tid == 0)   // announce publish AFTER the wave's publish instruction
        __hip_atomic_store(prog + b * 32 + s, (unsigned)(t + 1),
                           __ATOMIC_RELAXED, __HIP_MEMORY_SCOPE_AGENT);
    }
    // no 3rd barrier: finisher overlaps ring-mates' next poll
  }
}

// ---------- GEMM3: out = hs @ W_out + b_out ----------
__global__ __launch_bounds__(256) void k_gemm_out(const unsigned short* __restrict__ hs,
                                                  const unsigned short* __restrict__ WoT,
                                                  const float* __restrict__ b_out,
                                                  float* __restrict__ out) {
  __shared__ unsigned short At[128 * 32];
  __shared__ unsigned short Bt[128 * 32];
  const int tid = threadIdx.x;
  const int w = tid >> 6, l = tid & 63;
  const int wm = w >> 1, wn = w & 1;
  const int lr = l & 15, lk = (l >> 4) * 8;
  const int m0 = blockIdx.x * 128;
  const int n0 = blockIdx.y * 128;
  f32x4 acc[4][4];
#pragma unroll
  for (int mi = 0; mi < 4; mi++)
#pragma unroll
    for (int ni = 0; ni < 4; ni++)
#pragma unroll
      for (int e = 0; e < 4; e++) acc[mi][ni][e] = 0.f;

  const int sr = tid >> 2;
  const int skb = (tid & 3) * 8;
  for (int kt = 0; kt < 32; kt++) {
    const int k0 = kt * 32;
    gload_lds16(hs + (size_t)(m0 + sr) * 1024 + k0 + skb, &At[w * 512]);
    gload_lds16(hs + (size_t)(m0 + 64 + sr) * 1024 + k0 + skb, &At[2048 + w * 512]);
    gload_lds16(WoT + (size_t)(n0 + sr) * 1024 + k0 + skb, &Bt[w * 512]);
    gload_lds16(WoT + (size_t)(n0 + 64 + sr) * 1024 + k0 + skb, &Bt[2048 + w * 512]);
    __syncthreads();
    short8 Af[4], Bf[4];
#pragma unroll
    for (int mi = 0; mi < 4; mi++)
      Af[mi] = *(const short8*)&At[(wm * 64 + mi * 16 + lr) * 32 + lk];
#pragma unroll
    for (int ni = 0; ni < 4; ni++)
      Bf[ni] = *(const short8*)&Bt[(wn * 64 + ni * 16 + lr) * 32 + lk];
#pragma unroll
    for (int mi = 0; mi < 4; mi++)
#pragma unroll
      for (int ni = 0; ni < 4; ni++)
        acc[mi][ni] = mfma16(Af[mi], Bf[ni], acc[mi][ni]);
    __syncthreads();
  }
#pragma unroll
  for (int ni = 0; ni < 4; ni++) {
    const int c = n0 + wn * 64 + ni * 16 + lr;
    const float bo = b_out[c];
#pragma unroll
    for (int mi = 0; mi < 4; mi++) {
      const int r0 = m0 + wm * 64 + mi * 16 + (l >> 4) * 4;
#pragma unroll
      for (int e = 0; e < 4; e++)
        out[(size_t)(r0 + e) * 1024 + c] = acc[mi][ni][e] + bo;
    }
  }
}

// ---------- launch ----------
extern "C" void kernel_launch(void* const* d_in, const int* in_sizes, int n_in,
                              void* d_out, int out_size, void* d_ws, size_t ws_size,
                              hipStream_t stream) {
  const float* x      = (const float*)d_in[0];
  const float* h0     = (const float*)d_in[1];
  const float* W_in   = (const float*)d_in[2];
  const float* b_in   = (const float*)d_in[3];
  const float* W_gate = (const float*)d_in[4];
  const float* b_gate = (const float*)d_in[5];
  const float* W_rec  = (const float*)d_in[6];
  const float* b_rec  = (const float*)d_in[7];
  const float* W_out  = (const float*)d_in[8];
  const float* b_out  = (const float*)d_in[9];
  float* outp = (float*)d_out;

  size_t off = 0;
  auto alloc = [&](size_t bytes) {
    void* p = (char*)d_ws + off;
    off += (bytes + 255) & ~(size_t)255;
    return p;
  };
  unsigned short* xb    = (unsigned short*)alloc((size_t)16777216 * 2);
  unsigned short* WinT  = (unsigned short*)alloc((size_t)3072 * 1024 * 2);
  unsigned short* WgT   = (unsigned short*)alloc((size_t)2048 * 1024 * 2);
  unsigned short* WrT   = (unsigned short*)alloc((size_t)1024 * 1024 * 2);
  unsigned short* WoT   = (unsigned short*)alloc((size_t)1024 * 1024 * 2);
  unsigned short* drive = (unsigned short*)alloc((size_t)16777216 * 2);
  unsigned short* hs    = (unsigned short*)alloc((size_t)16777216 * 2);
  unsigned int*   hq    = (unsigned int*)alloc((size_t)8 * NPH * 1024 * 4);  // 256KB
  unsigned int*   prog  = (unsigned int*)alloc((size_t)256 * 4);

  // conversions / init
  k_cvt_bf16<<<16384, 256, 0, stream>>>(x, xb, 4194304);
  k_transpose_bf16<<<dim3(96, 32), 256, 0, stream>>>(W_in, WinT, 1024, 3072);
  k_transpose_bf16<<<dim3(64, 32), 256, 0, stream>>>(W_gate, WgT, 1024, 2048);
  k_transpose_bf16<<<dim3(32, 32), 256, 0, stream>>>(W_rec, WrT, 1024, 1024);
  k_transpose_bf16<<<dim3(32, 32), 256, 0, stream>>>(W_out, WoT, 1024, 1024);
  k_init_hq8<<<32, 256, 0, stream>>>(h0, hq);
  k_zero_prog<<<1, 256, 0, stream>>>(prog);

  // drive = silu(u)*silu(v)+w
  k_gemm_drive<<<dim3(128, 16), 256, 0, stream>>>(xb, WinT, b_in, drive);
  // sequential recurrence: 8 batch rings x 32 WGs, 8-phase skewed exchange
  k_scan<<<256, 1024, 0, stream>>>(WgT, WrT, b_gate, b_rec, drive, hq, prog,
                                   hs, outp + 16777216);
  // out = hs @ W_out + b_out
  k_gemm_out<<<dim3(128, 8), 256, 0, stream>>>(hs, WoT, b_out, outp);
}